// Round 8
// baseline (275.412 us; speedup 1.0000x reference)
//
#include <hip/hip_runtime.h>
#include <hip/hip_bf16.h>
#include <math.h>

#define BATCH 2048
#define SEQL 65
#define EMB 512
#define NHEADS 8
#define HD 64
#define NPATCH 64
#define PFEAT 48
#define HIDDIM 1024
#define NCLS 10

typedef short bfrag __attribute__((ext_vector_type(8)));   // 8 bf16 (4 VGPRs)
typedef float facc  __attribute__((ext_vector_type(16)));  // 16 f32 acc

union B8 { unsigned int u[4]; unsigned long long ull[2]; bfrag f; };

__device__ inline unsigned int cvt2(float a, float b) {     // 2x f32 -> packed bf16 (RTNE)
  __hip_bfloat162 t = __float22bfloat162_rn(float2{a, b});
  return *(unsigned int*)&t;
}
__device__ inline unsigned short f2bf(float f) {
  __hip_bfloat16 h = __float2bfloat16(f);
  return *(unsigned short*)&h;
}
__device__ inline float bf2f(unsigned short h) {
  return __uint_as_float(((unsigned int)h) << 16);
}
__device__ inline float lo16f(unsigned int u) { return __uint_as_float(u << 16); }
__device__ inline float hi16f(unsigned int u) { return __uint_as_float(u & 0xffff0000u); }
__device__ inline bfrag ldf(const unsigned short* p) {      // LDS: 2x ds_read_b64
  union { unsigned long long u[2]; bfrag s; } c;
  c.u[0] = *(const unsigned long long*)(p);
  c.u[1] = *(const unsigned long long*)(p + 4);
  return c.s;
}

// ---- K0: fused preprocessing.
// blocks [0,512): Wc = wq@proj_w -> bf16 hi/lo ; [512,1536): pack wo ; [1536,3584): pack w1 ;
// [3584,3840): transpose wq -> wqT[d][hk]
__global__ __launch_bounds__(256) void k_prep(
    const float* __restrict__ wq, const float* __restrict__ proj_w,
    unsigned short* __restrict__ WcH, unsigned short* __restrict__ WcL,
    const float* __restrict__ wo, unsigned short* __restrict__ WoH,
    unsigned short* __restrict__ WoL,
    const float* __restrict__ w1, unsigned short* __restrict__ W1H,
    unsigned short* __restrict__ W1L,
    float* __restrict__ wqT)
{
  __shared__ float sm[1088];
  const int bid = blockIdx.x, tid = threadIdx.x;
  if (bid < 512) {                       // ---- Wc pack (hk = bid) ----
    float* wr = sm;                      // 512
    float* part = sm + 512;              // 192
    const int hk = bid;
    wr[tid]     = wq[(size_t)hk*EMB + tid];
    wr[256+tid] = wq[(size_t)hk*EMB + 256 + tid];
    __syncthreads();
    if (tid < PFEAT*4) {
      int f = tid % PFEAT, p = tid / PFEAT;
      float a = 0.f;
      for (int d = p*128; d < (p+1)*128; ++d) a += wr[d]*proj_w[d*PFEAT + f];
      part[p*PFEAT + f] = a;
    }
    __syncthreads();
    if (tid < PFEAT) {
      float v = part[tid] + part[PFEAT+tid] + part[2*PFEAT+tid] + part[3*PFEAT+tid];
      unsigned short hi = f2bf(v);
      WcH[hk*PFEAT + tid] = hi;
      WcL[hk*PFEAT + tid] = f2bf(v - bf2f(hi));
    }
  } else if (bid < 1536) {               // ---- pack wo ----
    int i = (bid - 512)*256 + tid;
    float v = wo[i];
    unsigned short hi = f2bf(v);
    WoH[i] = hi; WoL[i] = f2bf(v - bf2f(hi));
  } else if (bid < 3584) {               // ---- pack w1 ----
    int i = (bid - 1536)*256 + tid;
    float v = w1[i];
    unsigned short hi = f2bf(v);
    W1H[i] = hi; W1L[i] = f2bf(v - bf2f(hi));
  } else {                               // ---- transpose wq (32x32 tiles) ----
    float (*t)[33] = (float(*)[33])sm;
    const int r = bid - 3584, bx = (r & 15)*32, by = (r >> 4)*32;
    const int c = tid & 31, r0 = tid >> 5;
    #pragma unroll
    for (int i = 0; i < 4; ++i) {
      int rr = r0 + 8*i;
      t[rr][c] = wq[(size_t)(by + rr)*512 + bx + c];
    }
    __syncthreads();
    #pragma unroll
    for (int i = 0; i < 4; ++i) {
      int rr = r0 + 8*i;
      wqT[(size_t)(bx + rr)*512 + by + c] = t[c][rr];
    }
  }
}

// ---- K0b: qbias[h][s][k] = (pos[s] + (s? proj_b : cls)) . wqT[:, h*64+k] + bq[h,k] ----
__global__ __launch_bounds__(256) void k_qbias(
    const float* __restrict__ wqT, const float* __restrict__ bq,
    const float* __restrict__ cls, const float* __restrict__ pos,
    const float* __restrict__ proj_b, float* __restrict__ qbias)
{
  __shared__ float v[EMB];
  __shared__ float part[256];
  const int h = blockIdx.x / SEQL, s = blockIdx.x - h*SEQL;
  const int tid = threadIdx.x;
  const float* po = pos + (size_t)s*EMB;
  v[tid]     = po[tid]     + (s == 0 ? cls[tid]     : proj_b[tid]);
  v[256+tid] = po[256+tid] + (s == 0 ? cls[256+tid] : proj_b[256+tid]);
  __syncthreads();
  const int p = tid >> 6, k = tid & 63;
  const float* wp = wqT + h*HD + k;
  float a = 0.f;
  for (int d = p*128; d < p*128 + 128; ++d)
    a = fmaf(v[d], wp[(size_t)d*512], a);
  part[p*64 + k] = a;
  __syncthreads();
  if (tid < HD)
    qbias[((size_t)h*SEQL + s)*HD + tid] =
        part[tid] + part[64+tid] + part[128+tid] + part[192+tid] + bq[h*HD + tid];
}

// ---- K1: block per (b,h), id = h*2048+b. Direct-from-global A-frags; Q bf16 in LDS;
// S never materialized (flash partials). Output mh0 written as split-bf16 (hi/lo).
// LDS: Qh[96*68]u16 13056 | mpart[6*96] | spart[6*96] | S0[96] | p0[96] | attp[256] = 19456 B
__global__ __launch_bounds__(256) void k_attn(
    const float* __restrict__ x, const unsigned short* __restrict__ WcH,
    const unsigned short* __restrict__ WcL, const float* __restrict__ qbias,
    unsigned short* __restrict__ mh0H, unsigned short* __restrict__ mh0L)
{
  __shared__ __align__(16) char smem[19456];
  unsigned short* Qh = (unsigned short*)smem;           // 96*68 u16
  float* mpart = (float*)(smem + 13056);                // 6*96
  float* spart = (float*)(smem + 15360);                // 6*96
  float* S0    = (float*)(smem + 17664);                // 96
  float* p0v   = (float*)(smem + 18048);                // 96
  float* attp  = (float*)(smem + 18432);                // 256

  const int b = blockIdx.x & 2047, h = blockIdx.x >> 11;
  const int tid = threadIdx.x, w = tid >> 6, lane = tid & 63;
  const int u2 = lane >> 5;            // k-fragment half (0/1)
  const float* xb = x + (size_t)b*3072;
  const float* qb = qbias + (size_t)h*SEQL*HD;
  const float C = 0.18033688011112042f;   // log2(e)/8

  // ---- stage 1: q = P·Wc_h^T + qbias; A from global, B from global/L2 ----
  {
    const int ti = w >> 1, tj = w & 1;
    const int ar = 32*ti + (lane & 31);          // patch row
    const int ni = ar >> 3, nj = ar & 7;
    const float* pbase = xb + (ni*4 + 2*u2)*32 + nj*4;
    const int br = 32*tj + (lane & 31);          // q-dim
    const unsigned short* whp = WcH + ((size_t)(h*HD + br))*PFEAT;
    const unsigned short* wlp = WcL + ((size_t)(h*HD + br))*PFEAT;
    facc acc = {0,0,0,0,0,0,0,0,0,0,0,0,0,0,0,0};
    #pragma unroll
    for (int ks = 0; ks < 3; ++ks) {             // ks == color channel
      float4 va = *(const float4*)(pbase + ks*1024);
      float4 vb = *(const float4*)(pbase + ks*1024 + 32);
      B8 ah, al;
      ah.u[0] = cvt2(va.x, va.y); ah.u[1] = cvt2(va.z, va.w);
      ah.u[2] = cvt2(vb.x, vb.y); ah.u[3] = cvt2(vb.z, vb.w);
      al.u[0] = cvt2(va.x - lo16f(ah.u[0]), va.y - hi16f(ah.u[0]));
      al.u[1] = cvt2(va.z - lo16f(ah.u[1]), va.w - hi16f(ah.u[1]));
      al.u[2] = cvt2(vb.x - lo16f(ah.u[2]), vb.y - hi16f(ah.u[2]));
      al.u[3] = cvt2(vb.z - lo16f(ah.u[3]), vb.w - hi16f(ah.u[3]));
      const int f0 = ks*16 + u2*8;
      B8 bh, bl;
      bh.f = *(const bfrag*)(whp + f0);
      bl.f = *(const bfrag*)(wlp + f0);
      acc = __builtin_amdgcn_mfma_f32_32x32x16_bf16(ah.f, bh.f, acc, 0, 0, 0);
      acc = __builtin_amdgcn_mfma_f32_32x32x16_bf16(ah.f, bl.f, acc, 0, 0, 0);
      acc = __builtin_amdgcn_mfma_f32_32x32x16_bf16(al.f, bh.f, acc, 0, 0, 0);
    }
    #pragma unroll
    for (int r = 0; r < 16; ++r) {
      int row = (r & 3) + 8*(r >> 2) + 4*u2 + 32*ti;
      int s = 1 + row;
      Qh[s*68 + br] = f2bf(acc[r] + qb[s*HD + br]);
    }
    if (tid < HD) Qh[tid] = f2bf(qb[tid]);       // cls row s=0
    for (int i = tid; i < 31*17; i += 256) {     // zero rows 65..95
      int row = 65 + i/17, o = (i - (i/17)*17)*4;
      *(unsigned long long*)(Qh + row*68 + o) = 0ull;
    }
  }
  __syncthreads();   // A: Q complete

  // ---- stage 2: per-tile MFMA + in-register column stats (flash partials) ----
  for (int t = w; t < 9; t += 4) {
    const int ri = t/3, ci = t - ri*3;
    const int ar2 = 32*ri + (lane & 31);
    const int br2 = 32*ci + (lane & 31);     // this lane's column
    facc a2 = {0,0,0,0,0,0,0,0,0,0,0,0,0,0,0,0};
    #pragma unroll
    for (int ks = 0; ks < 4; ++ks) {
      int k0 = ks*16 + u2*8;
      bfrag qa = ldf(Qh + ar2*68 + k0);
      bfrag qc = ldf(Qh + br2*68 + k0);
      a2 = __builtin_amdgcn_mfma_f32_32x32x16_bf16(qa, qc, a2, 0, 0, 0);
    }
    float m, s;
    if (ri == 2) {                // only row 64 valid (reg 0, lanes<32)
      m = (u2 == 0) ? a2[0] : -3.0e38f;
      s = (u2 == 0) ? 1.0f : 0.0f;
    } else {
      m = a2[0];
      #pragma unroll
      for (int r = 1; r < 16; ++r) m = fmaxf(m, a2[r]);
      float mm = m * C;
      s = 0.f;
      #pragma unroll
      for (int r = 0; r < 16; ++r)
        s += __builtin_amdgcn_exp2f(fmaf(a2[r], C, -mm));
    }
    const int pi = ri*2 + u2;
    mpart[pi*96 + br2] = m;
    spart[pi*96 + br2] = s;
    if (ri == 0 && u2 == 0) S0[br2] = a2[0];   // S[0][col] (raw)
  }
  __syncthreads();   // B

  // ---- merge partials -> p0 (only columns < 65 used) ----
  if (tid < SEQL) {
    float m = mpart[tid];
    #pragma unroll
    for (int i = 1; i < 6; ++i) m = fmaxf(m, mpart[i*96 + tid]);
    float mm = m * C;
    float s = 0.f;
    #pragma unroll
    for (int i = 0; i < 6; ++i)
      s += spart[i*96 + tid] * __builtin_amdgcn_exp2f(fmaf(mpart[i*96 + tid], C, -mm));
    p0v[tid] = __builtin_amdgcn_exp2f(fmaf(S0[tid], C, -mm)) / s;
  }
  __syncthreads();   // C

  // ---- att0[k] = sum_t p0[t]*q[t][k] (4 partials) ----
  {
    int k = tid & 63, p = tid >> 6;
    int t0 = p*17, t1 = (t0 + 17 < SEQL) ? t0 + 17 : SEQL;
    float a = 0.f;
    for (int t = t0; t < t1; ++t)
      a += p0v[t] * bf2f(Qh[t*68 + k]);
    attp[p*64 + k] = a;
  }
  __syncthreads();   // D
  if (tid < HD) {
    float a = attp[tid] + attp[64+tid] + attp[128+tid] + attp[192+tid];
    unsigned short hi = f2bf(a);
    mh0H[(size_t)b*EMB + h*HD + tid] = hi;
    mh0L[(size_t)b*EMB + h*HD + tid] = f2bf(a - bf2f(hi));
  }
}

// ---- K2/K3: barrier-free split-K MFMA GEMM on pre-split bf16 operands.
// Each wave: 32x32 output tile over K/4 chunk, frags straight from global/L2.
// 4-wave combine via 16KB LDS + one barrier. GELU variant writes f32; other splits.
template<bool GELU>
__global__ __launch_bounds__(256) void k_gemm(
    const unsigned short* __restrict__ AH, const unsigned short* __restrict__ AL,
    const unsigned short* __restrict__ WH, const unsigned short* __restrict__ WL,
    const float* __restrict__ bias, float* __restrict__ Cf,
    unsigned short* __restrict__ CH, unsigned short* __restrict__ CL,
    int N, int K)
{
  __shared__ float red[4096];
  const int tid = threadIdx.x, w = tid >> 6, lane = tid & 63;
  const int u2 = lane >> 5;
  const int m0 = blockIdx.x*32, n0 = blockIdx.y*32;
  const int kb = w*(K >> 2);
  const unsigned short* ahp = AH + (size_t)(m0 + (lane & 31))*K + kb + u2*8;
  const unsigned short* alp = AL + (size_t)(m0 + (lane & 31))*K + kb + u2*8;
  const unsigned short* bhp = WH + (size_t)(n0 + (lane & 31))*K + kb + u2*8;
  const unsigned short* blp = WL + (size_t)(n0 + (lane & 31))*K + kb + u2*8;
  facc acc = {0,0,0,0,0,0,0,0,0,0,0,0,0,0,0,0};
  const int kc = K >> 2;
  for (int k = 0; k < kc; k += 16) {
    bfrag ah = *(const bfrag*)(ahp + k);
    bfrag al = *(const bfrag*)(alp + k);
    bfrag bh = *(const bfrag*)(bhp + k);
    bfrag bl = *(const bfrag*)(blp + k);
    acc = __builtin_amdgcn_mfma_f32_32x32x16_bf16(ah, bh, acc, 0, 0, 0);
    acc = __builtin_amdgcn_mfma_f32_32x32x16_bf16(ah, bl, acc, 0, 0, 0);
    acc = __builtin_amdgcn_mfma_f32_32x32x16_bf16(al, bh, acc, 0, 0, 0);
  }
  #pragma unroll
  for (int r = 0; r < 16; ++r) red[(w*16 + r)*64 + lane] = acc[r];
  __syncthreads();
  #pragma unroll
  for (int e0 = 0; e0 < 4; ++e0) {
    int e = e0*256 + tid;
    int r = e >> 6, l = e & 63;
    float c = red[e] + red[1024+e] + red[2048+e] + red[3072+e];
    int row = m0 + (r & 3) + 8*(r >> 2) + 4*(l >> 5);
    int col = n0 + (l & 31);
    c += bias[col];
    if (GELU) {
      c = 0.5f*c*(1.f + erff(c*0.70710678118654752f));
      Cf[(size_t)row*N + col] = c;
    } else {
      unsigned short hi = f2bf(c);
      CH[(size_t)row*N + col] = hi;
      CL[(size_t)row*N + col] = f2bf(c - bf2f(hi));
    }
  }
}

// ---- K4: logits = hh @ w2^T + b2 ; one wave per batch row ----
__global__ __launch_bounds__(256) void k_logits(
    const float* __restrict__ hh, const float* __restrict__ w2,
    const float* __restrict__ b2, float* __restrict__ out)
{
  const int w = threadIdx.x >> 6, lane = threadIdx.x & 63;
  const int r = blockIdx.x*4 + w;
  const float* hr = hh + (size_t)r*HIDDIM + lane*16;
  float hv[16];
  #pragma unroll
  for (int i4 = 0; i4 < 4; ++i4) {
    float4 v = *(const float4*)(hr + i4*4);
    hv[i4*4+0] = v.x; hv[i4*4+1] = v.y; hv[i4*4+2] = v.z; hv[i4*4+3] = v.w;
  }
  float acc[NCLS];
  #pragma unroll
  for (int c = 0; c < NCLS; ++c) {
    const float* wr = w2 + (size_t)c*HIDDIM + lane*16;
    float a = 0.f;
    #pragma unroll
    for (int i4 = 0; i4 < 4; ++i4) {
      float4 wv = *(const float4*)(wr + i4*4);
      a += hv[i4*4]*wv.x + hv[i4*4+1]*wv.y + hv[i4*4+2]*wv.z + hv[i4*4+3]*wv.w;
    }
    acc[c] = a;
  }
  #pragma unroll
  for (int c = 0; c < NCLS; ++c)
    #pragma unroll
    for (int m = 1; m < 64; m <<= 1) acc[c] += __shfl_xor(acc[c], m, 64);
  if (lane == 0) {
    #pragma unroll
    for (int c = 0; c < NCLS; ++c) out[(size_t)r*NCLS + c] = acc[c] + b2[c];
  }
}

extern "C" void kernel_launch(void* const* d_in, const int* in_sizes, int n_in,
                              void* d_out, int out_size, void* d_ws, size_t ws_size,
                              hipStream_t stream)
{
  const float* x      = (const float*)d_in[0];
  const float* proj_w = (const float*)d_in[1];
  const float* proj_b = (const float*)d_in[2];
  const float* cls    = (const float*)d_in[3];
  const float* pos    = (const float*)d_in[4];
  const float* wq     = (const float*)d_in[5];
  const float* bq     = (const float*)d_in[6];
  const float* wo     = (const float*)d_in[7];
  const float* bo     = (const float*)d_in[8];
  const float* w1     = (const float*)d_in[9];
  const float* b1     = (const float*)d_in[10];
  const float* w2     = (const float*)d_in[11];
  const float* b2     = (const float*)d_in[12];
  float* out = (float*)d_out;

  // ws layout (bytes), total 20,154,368 (same as round 7).
  // mh0 region now holds mh0H|mh0L (2MB+2MB); ct region holds ctH|ctL (2MB+2MB).
  // wqT overlays hh: written by k_prep, read by k_qbias, overwritten by gemm<true>.
  unsigned short* WcH = (unsigned short*)d_ws;                         // 49152
  unsigned short* WcL = (unsigned short*)((char*)d_ws + 49152);        // 49152
  float* qbias        = (float*)((char*)d_ws + 98304);                 // 133120
  unsigned short* WoH = (unsigned short*)((char*)d_ws + 231424);       // 524288
  unsigned short* WoL = (unsigned short*)((char*)d_ws + 755712);       // 524288
  unsigned short* W1H = (unsigned short*)((char*)d_ws + 1280000);      // 1048576
  unsigned short* W1L = (unsigned short*)((char*)d_ws + 2328576);      // 1048576
  unsigned short* mh0H = (unsigned short*)((char*)d_ws + 3377152);     // 2MB
  unsigned short* mh0L = (unsigned short*)((char*)d_ws + 5474304);     // 2MB
  unsigned short* ctH  = (unsigned short*)((char*)d_ws + 7571456);     // 2MB
  unsigned short* ctL  = (unsigned short*)((char*)d_ws + 9668608);     // 2MB
  float* hh           = (float*)((char*)d_ws + 11765760);              // 8 MB
  float* wqT          = hh;                                            // 1 MB overlay

  hipLaunchKernelGGL(k_prep, dim3(3840), dim3(256), 0, stream,
                     wq, proj_w, WcH, WcL, wo, WoH, WoL, w1, W1H, W1L, wqT);
  hipLaunchKernelGGL(k_qbias, dim3(NHEADS*SEQL), dim3(256), 0, stream,
                     wqT, bq, cls, pos, proj_b, qbias);
  hipLaunchKernelGGL(k_attn, dim3(BATCH*NHEADS), dim3(256), 0, stream,
                     x, WcH, WcL, qbias, mh0H, mh0L);
  hipLaunchKernelGGL((k_gemm<false>), dim3(BATCH/32, EMB/32), dim3(256), 0, stream,
                     mh0H, mh0L, WoH, WoL, bo, (float*)nullptr, ctH, ctL, EMB, EMB);
  hipLaunchKernelGGL((k_gemm<true>),  dim3(BATCH/32, HIDDIM/32), dim3(256), 0, stream,
                     ctH, ctL, W1H, W1L, b1, hh, (unsigned short*)nullptr,
                     (unsigned short*)nullptr, HIDDIM, EMB);
  hipLaunchKernelGGL(k_logits, dim3(BATCH/4), dim3(256), 0, stream,
                     hh, w2, b2, out);
}

// Round 9
// 252.606 us; speedup vs baseline: 1.0903x; 1.0903x over previous
//
#include <hip/hip_runtime.h>
#include <hip/hip_bf16.h>
#include <math.h>

#define BATCH 2048
#define SEQL 65
#define EMB 512
#define NHEADS 8
#define HD 64
#define NPATCH 64
#define PFEAT 48
#define HIDDIM 1024
#define NCLS 10

typedef short bfrag __attribute__((ext_vector_type(8)));   // 8 bf16 (4 VGPRs)
typedef float facc  __attribute__((ext_vector_type(16)));  // 16 f32 acc

union B8 { unsigned int u[4]; unsigned long long ull[2]; bfrag f; };

__device__ inline unsigned int cvt2(float a, float b) {     // 2x f32 -> packed bf16 (RTNE)
  __hip_bfloat162 t = __float22bfloat162_rn(float2{a, b});
  return *(unsigned int*)&t;
}
__device__ inline unsigned short f2bf(float f) {
  __hip_bfloat16 h = __float2bfloat16(f);
  return *(unsigned short*)&h;
}
__device__ inline float bf2f(unsigned short h) {
  return __uint_as_float(((unsigned int)h) << 16);
}
__device__ inline float lo16f(unsigned int u) { return __uint_as_float(u << 16); }
__device__ inline float hi16f(unsigned int u) { return __uint_as_float(u & 0xffff0000u); }
__device__ inline bfrag ldf(const unsigned short* p) {      // LDS: 2x ds_read_b64
  union { unsigned long long u[2]; bfrag s; } c;
  c.u[0] = *(const unsigned long long*)(p);
  c.u[1] = *(const unsigned long long*)(p + 4);
  return c.s;
}
__device__ inline void split8(const float* v, B8& h, B8& l) {
  h.u[0] = cvt2(v[0], v[1]); h.u[1] = cvt2(v[2], v[3]);
  h.u[2] = cvt2(v[4], v[5]); h.u[3] = cvt2(v[6], v[7]);
  l.u[0] = cvt2(v[0]-lo16f(h.u[0]), v[1]-hi16f(h.u[0]));
  l.u[1] = cvt2(v[2]-lo16f(h.u[1]), v[3]-hi16f(h.u[1]));
  l.u[2] = cvt2(v[4]-lo16f(h.u[2]), v[5]-hi16f(h.u[2]));
  l.u[3] = cvt2(v[6]-lo16f(h.u[3]), v[7]-hi16f(h.u[3]));
}

// ---- K0: prep. blocks [0,512): Wc = wq@proj_w -> bf16 hi/lo; [512,768): transpose wq -> wqT
__global__ __launch_bounds__(256) void k_prep(
    const float* __restrict__ wq, const float* __restrict__ proj_w,
    unsigned short* __restrict__ WcH, unsigned short* __restrict__ WcL,
    float* __restrict__ wqT)
{
  __shared__ float sm[1088];
  const int bid = blockIdx.x, tid = threadIdx.x;
  if (bid < 512) {                       // ---- Wc pack (hk = bid) ----
    float* wr = sm;                      // 512
    float* part = sm + 512;              // 192
    const int hk = bid;
    wr[tid]     = wq[(size_t)hk*EMB + tid];
    wr[256+tid] = wq[(size_t)hk*EMB + 256 + tid];
    __syncthreads();
    if (tid < PFEAT*4) {
      int f = tid % PFEAT, p = tid / PFEAT;
      float a = 0.f;
      for (int d = p*128; d < (p+1)*128; ++d) a += wr[d]*proj_w[d*PFEAT + f];
      part[p*PFEAT + f] = a;
    }
    __syncthreads();
    if (tid < PFEAT) {
      float v = part[tid] + part[PFEAT+tid] + part[2*PFEAT+tid] + part[3*PFEAT+tid];
      unsigned short hi = f2bf(v);
      WcH[hk*PFEAT + tid] = hi;
      WcL[hk*PFEAT + tid] = f2bf(v - bf2f(hi));
    }
  } else {                               // ---- transpose wq (32x32 tiles) ----
    float (*t)[33] = (float(*)[33])sm;
    const int r = bid - 512, bx = (r & 15)*32, by = (r >> 4)*32;
    const int c = tid & 31, r0 = tid >> 5;
    #pragma unroll
    for (int i = 0; i < 4; ++i) {
      int rr = r0 + 8*i;
      t[rr][c] = wq[(size_t)(by + rr)*512 + bx + c];
    }
    __syncthreads();
    #pragma unroll
    for (int i = 0; i < 4; ++i) {
      int rr = r0 + 8*i;
      wqT[(size_t)(bx + rr)*512 + by + c] = t[c][rr];
    }
  }
}

// ---- K0b: qbias[h][s][k] = (pos[s] + (s? proj_b : cls)) . wqT[:, h*64+k] + bq[h,k] ----
__global__ __launch_bounds__(256) void k_qbias(
    const float* __restrict__ wqT, const float* __restrict__ bq,
    const float* __restrict__ cls, const float* __restrict__ pos,
    const float* __restrict__ proj_b, float* __restrict__ qbias)
{
  __shared__ float v[EMB];
  __shared__ float part[256];
  const int h = blockIdx.x / SEQL, s = blockIdx.x - h*SEQL;
  const int tid = threadIdx.x;
  const float* po = pos + (size_t)s*EMB;
  v[tid]     = po[tid]     + (s == 0 ? cls[tid]     : proj_b[tid]);
  v[256+tid] = po[256+tid] + (s == 0 ? cls[256+tid] : proj_b[256+tid]);
  __syncthreads();
  const int p = tid >> 6, k = tid & 63;
  const float* wp = wqT + h*HD + k;
  float a = 0.f;
  for (int d = p*128; d < p*128 + 128; ++d)
    a = fmaf(v[d], wp[(size_t)d*512], a);
  part[p*64 + k] = a;
  __syncthreads();
  if (tid < HD)
    qbias[((size_t)h*SEQL + s)*HD + tid] =
        part[tid] + part[64+tid] + part[128+tid] + part[192+tid] + bq[h*HD + tid];
}

// ---- K0c: W1c = w1 @ wo, split-bf16 MFMA; output pre-split [HID][EMB] ----
__global__ __launch_bounds__(256) void k_fuse(
    const float* __restrict__ w1, const float* __restrict__ wo,
    unsigned short* __restrict__ W1cH, unsigned short* __restrict__ W1cL)
{
  __shared__ float woT[64*65];
  const int tid = threadIdx.x, w = tid >> 6, lane = tid & 63;
  const int u2 = lane >> 5;
  const int i0 = blockIdx.x*64, d0 = blockIdx.y*64;
  const int ti = w >> 1, tj = w & 1;
  const int ar = i0 + 32*ti + (lane & 31);   // w1 row
  const int brl = 32*tj + (lane & 31);       // local d
  const int jr = tid >> 3, d4 = (tid & 7)*8;
  facc acc = {0,0,0,0,0,0,0,0,0,0,0,0,0,0,0,0};
  for (int j0 = 0; j0 < EMB; j0 += 64) {
    __syncthreads();
    #pragma unroll
    for (int p = 0; p < 2; ++p) {
      int j = j0 + p*32 + jr;
      const float* wp = wo + (size_t)j*EMB + d0 + d4;
      float4 v0 = *(const float4*)(wp);
      float4 v1 = *(const float4*)(wp + 4);
      int jc = p*32 + jr;
      woT[(d4+0)*65 + jc] = v0.x; woT[(d4+1)*65 + jc] = v0.y;
      woT[(d4+2)*65 + jc] = v0.z; woT[(d4+3)*65 + jc] = v0.w;
      woT[(d4+4)*65 + jc] = v1.x; woT[(d4+5)*65 + jc] = v1.y;
      woT[(d4+6)*65 + jc] = v1.z; woT[(d4+7)*65 + jc] = v1.w;
    }
    __syncthreads();
    #pragma unroll
    for (int ks = 0; ks < 4; ++ks) {
      const int jf = ks*16 + u2*8;
      const float* ap = w1 + (size_t)ar*EMB + j0 + jf;
      float4 a0 = *(const float4*)(ap);
      float4 a1 = *(const float4*)(ap + 4);
      float av[8] = {a0.x,a0.y,a0.z,a0.w,a1.x,a1.y,a1.z,a1.w};
      float bv[8];
      #pragma unroll
      for (int e = 0; e < 8; ++e) bv[e] = woT[brl*65 + jf + e];
      B8 ah, al, bh, bl;
      split8(av, ah, al); split8(bv, bh, bl);
      acc = __builtin_amdgcn_mfma_f32_32x32x16_bf16(ah.f, bh.f, acc, 0, 0, 0);
      acc = __builtin_amdgcn_mfma_f32_32x32x16_bf16(ah.f, bl.f, acc, 0, 0, 0);
      acc = __builtin_amdgcn_mfma_f32_32x32x16_bf16(al.f, bh.f, acc, 0, 0, 0);
    }
  }
  #pragma unroll
  for (int r = 0; r < 16; ++r) {
    int row = i0 + 32*ti + (r & 3) + 8*(r >> 2) + 4*u2;
    int col = d0 + brl;
    float v = acc[r];
    unsigned short hi = f2bf(v);
    W1cH[(size_t)row*EMB + col] = hi;
    W1cL[(size_t)row*EMB + col] = f2bf(v - bf2f(hi));
  }
}

// ---- K0d: b1c = b1 + w1 @ bo ----
__global__ __launch_bounds__(256) void k_b1c(
    const float* __restrict__ w1, const float* __restrict__ bo,
    const float* __restrict__ b1, float* __restrict__ b1c)
{
  int i = blockIdx.x*256 + threadIdx.x;
  const float* wr = w1 + (size_t)i*EMB;
  float a = b1[i];
  for (int j = 0; j < EMB; j += 4) {
    float4 wv = *(const float4*)(wr + j);
    float4 bv = *(const float4*)(bo + j);
    a += wv.x*bv.x + wv.y*bv.y + wv.z*bv.z + wv.w*bv.w;
  }
  b1c[i] = a;
}

// ---- K1: block per (b,h), id = h*2048+b. Direct-from-global A-frags; Q bf16 in LDS;
// S never materialized (flash partials). Output mh0 written as split-bf16 (hi/lo).
// LDS: Qh[96*68]u16 13056 | mpart[6*96] | spart[6*96] | S0[96] | p0[96] | attp[256] = 19456 B
__global__ __launch_bounds__(256) void k_attn(
    const float* __restrict__ x, const unsigned short* __restrict__ WcH,
    const unsigned short* __restrict__ WcL, const float* __restrict__ qbias,
    unsigned short* __restrict__ mh0H, unsigned short* __restrict__ mh0L)
{
  __shared__ __align__(16) char smem[19456];
  unsigned short* Qh = (unsigned short*)smem;           // 96*68 u16
  float* mpart = (float*)(smem + 13056);                // 6*96
  float* spart = (float*)(smem + 15360);                // 6*96
  float* S0    = (float*)(smem + 17664);                // 96
  float* p0v   = (float*)(smem + 18048);                // 96
  float* attp  = (float*)(smem + 18432);                // 256

  const int b = blockIdx.x & 2047, h = blockIdx.x >> 11;
  const int tid = threadIdx.x, w = tid >> 6, lane = tid & 63;
  const int u2 = lane >> 5;            // k-fragment half (0/1)
  const float* xb = x + (size_t)b*3072;
  const float* qb = qbias + (size_t)h*SEQL*HD;
  const float C = 0.18033688011112042f;   // log2(e)/8

  // ---- stage 1: q = P·Wc_h^T + qbias; A from global, B from global/L2 ----
  {
    const int ti = w >> 1, tj = w & 1;
    const int ar = 32*ti + (lane & 31);          // patch row
    const int ni = ar >> 3, nj = ar & 7;
    const float* pbase = xb + (ni*4 + 2*u2)*32 + nj*4;
    const int br = 32*tj + (lane & 31);          // q-dim
    const unsigned short* whp = WcH + ((size_t)(h*HD + br))*PFEAT;
    const unsigned short* wlp = WcL + ((size_t)(h*HD + br))*PFEAT;
    facc acc = {0,0,0,0,0,0,0,0,0,0,0,0,0,0,0,0};
    #pragma unroll
    for (int ks = 0; ks < 3; ++ks) {             // ks == color channel
      float4 va = *(const float4*)(pbase + ks*1024);
      float4 vb = *(const float4*)(pbase + ks*1024 + 32);
      B8 ah, al;
      ah.u[0] = cvt2(va.x, va.y); ah.u[1] = cvt2(va.z, va.w);
      ah.u[2] = cvt2(vb.x, vb.y); ah.u[3] = cvt2(vb.z, vb.w);
      al.u[0] = cvt2(va.x - lo16f(ah.u[0]), va.y - hi16f(ah.u[0]));
      al.u[1] = cvt2(va.z - lo16f(ah.u[1]), va.w - hi16f(ah.u[1]));
      al.u[2] = cvt2(vb.x - lo16f(ah.u[2]), vb.y - hi16f(ah.u[2]));
      al.u[3] = cvt2(vb.z - lo16f(ah.u[3]), vb.w - hi16f(ah.u[3]));
      const int f0 = ks*16 + u2*8;
      B8 bh, bl;
      bh.f = *(const bfrag*)(whp + f0);
      bl.f = *(const bfrag*)(wlp + f0);
      acc = __builtin_amdgcn_mfma_f32_32x32x16_bf16(ah.f, bh.f, acc, 0, 0, 0);
      acc = __builtin_amdgcn_mfma_f32_32x32x16_bf16(ah.f, bl.f, acc, 0, 0, 0);
      acc = __builtin_amdgcn_mfma_f32_32x32x16_bf16(al.f, bh.f, acc, 0, 0, 0);
    }
    #pragma unroll
    for (int r = 0; r < 16; ++r) {
      int row = (r & 3) + 8*(r >> 2) + 4*u2 + 32*ti;
      int s = 1 + row;
      Qh[s*68 + br] = f2bf(acc[r] + qb[s*HD + br]);
    }
    if (tid < HD) Qh[tid] = f2bf(qb[tid]);       // cls row s=0
    for (int i = tid; i < 31*17; i += 256) {     // zero rows 65..95
      int row = 65 + i/17, o = (i - (i/17)*17)*4;
      *(unsigned long long*)(Qh + row*68 + o) = 0ull;
    }
  }
  __syncthreads();   // A: Q complete

  // ---- stage 2: per-tile MFMA + in-register column stats (flash partials) ----
  for (int t = w; t < 9; t += 4) {
    const int ri = t/3, ci = t - ri*3;
    const int ar2 = 32*ri + (lane & 31);
    const int br2 = 32*ci + (lane & 31);     // this lane's column
    facc a2 = {0,0,0,0,0,0,0,0,0,0,0,0,0,0,0,0};
    #pragma unroll
    for (int ks = 0; ks < 4; ++ks) {
      int k0 = ks*16 + u2*8;
      bfrag qa = ldf(Qh + ar2*68 + k0);
      bfrag qc = ldf(Qh + br2*68 + k0);
      a2 = __builtin_amdgcn_mfma_f32_32x32x16_bf16(qa, qc, a2, 0, 0, 0);
    }
    float m, s;
    if (ri == 2) {                // only row 64 valid (reg 0, lanes<32)
      m = (u2 == 0) ? a2[0] : -3.0e38f;
      s = (u2 == 0) ? 1.0f : 0.0f;
    } else {
      m = a2[0];
      #pragma unroll
      for (int r = 1; r < 16; ++r) m = fmaxf(m, a2[r]);
      float mm = m * C;
      s = 0.f;
      #pragma unroll
      for (int r = 0; r < 16; ++r)
        s += __builtin_amdgcn_exp2f(fmaf(a2[r], C, -mm));
    }
    const int pi = ri*2 + u2;
    mpart[pi*96 + br2] = m;
    spart[pi*96 + br2] = s;
    if (ri == 0 && u2 == 0) S0[br2] = a2[0];   // S[0][col] (raw)
  }
  __syncthreads();   // B

  // ---- merge partials -> p0 (only columns < 65 used) ----
  if (tid < SEQL) {
    float m = mpart[tid];
    #pragma unroll
    for (int i = 1; i < 6; ++i) m = fmaxf(m, mpart[i*96 + tid]);
    float mm = m * C;
    float s = 0.f;
    #pragma unroll
    for (int i = 0; i < 6; ++i)
      s += spart[i*96 + tid] * __builtin_amdgcn_exp2f(fmaf(mpart[i*96 + tid], C, -mm));
    p0v[tid] = __builtin_amdgcn_exp2f(fmaf(S0[tid], C, -mm)) / s;
  }
  __syncthreads();   // C

  // ---- att0[k] = sum_t p0[t]*q[t][k] (4 partials) ----
  {
    int k = tid & 63, p = tid >> 6;
    int t0 = p*17, t1 = (t0 + 17 < SEQL) ? t0 + 17 : SEQL;
    float a = 0.f;
    for (int t = t0; t < t1; ++t)
      a += p0v[t] * bf2f(Qh[t*68 + k]);
    attp[p*64 + k] = a;
  }
  __syncthreads();   // D
  if (tid < HD) {
    float a = attp[tid] + attp[64+tid] + attp[128+tid] + attp[192+tid];
    unsigned short hi = f2bf(a);
    mh0H[(size_t)b*EMB + h*HD + tid] = hi;
    mh0L[(size_t)b*EMB + h*HD + tid] = f2bf(a - bf2f(hi));
  }
}

// ---- K2: hh = gelu(mh0 @ W1c^T + b1c). Pre-split operands, LDS-staged both sides.
__global__ __launch_bounds__(256) void k_gemm2(
    const unsigned short* __restrict__ AH, const unsigned short* __restrict__ AL,
    const unsigned short* __restrict__ BH, const unsigned short* __restrict__ BL,
    const float* __restrict__ bias, float* __restrict__ C, int N, int K)
{
  __shared__ __align__(16) unsigned short sAh[64*68];
  __shared__ __align__(16) unsigned short sAl[64*68];
  __shared__ __align__(16) unsigned short sBh[64*68];
  __shared__ __align__(16) unsigned short sBl[64*68];
  const int tid = threadIdx.x, w = tid >> 6, lane = tid & 63;
  const int u2 = lane >> 5;
  const int m0 = blockIdx.x*64, n0 = blockIdx.y*64;
  const int ti = w >> 1, tj = w & 1;
  const int arl = 32*ti + (lane & 31);
  const int brl = 32*tj + (lane & 31);
  const int srow = tid >> 3, scol = (tid & 7)*8;
  facc acc = {0,0,0,0,0,0,0,0,0,0,0,0,0,0,0,0};
  for (int k0 = 0; k0 < K; k0 += 64) {
    __syncthreads();
    #pragma unroll
    for (int p = 0; p < 2; ++p) {
      int row = p*32 + srow;
      B8 va, vb, vc, vd;
      va.f = *(const bfrag*)(AH + (size_t)(m0+row)*K + k0 + scol);
      vb.f = *(const bfrag*)(AL + (size_t)(m0+row)*K + k0 + scol);
      vc.f = *(const bfrag*)(BH + (size_t)(n0+row)*K + k0 + scol);
      vd.f = *(const bfrag*)(BL + (size_t)(n0+row)*K + k0 + scol);
      *(unsigned long long*)(sAh + row*68 + scol)     = va.ull[0];
      *(unsigned long long*)(sAh + row*68 + scol + 4) = va.ull[1];
      *(unsigned long long*)(sAl + row*68 + scol)     = vb.ull[0];
      *(unsigned long long*)(sAl + row*68 + scol + 4) = vb.ull[1];
      *(unsigned long long*)(sBh + row*68 + scol)     = vc.ull[0];
      *(unsigned long long*)(sBh + row*68 + scol + 4) = vc.ull[1];
      *(unsigned long long*)(sBl + row*68 + scol)     = vd.ull[0];
      *(unsigned long long*)(sBl + row*68 + scol + 4) = vd.ull[1];
    }
    __syncthreads();
    #pragma unroll
    for (int ks = 0; ks < 4; ++ks) {
      int jf = ks*16 + u2*8;
      bfrag ah = ldf(sAh + arl*68 + jf);
      bfrag al = ldf(sAl + arl*68 + jf);
      bfrag bh = ldf(sBh + brl*68 + jf);
      bfrag bl = ldf(sBl + brl*68 + jf);
      acc = __builtin_amdgcn_mfma_f32_32x32x16_bf16(ah, bh, acc, 0, 0, 0);
      acc = __builtin_amdgcn_mfma_f32_32x32x16_bf16(ah, bl, acc, 0, 0, 0);
      acc = __builtin_amdgcn_mfma_f32_32x32x16_bf16(al, bh, acc, 0, 0, 0);
    }
  }
  #pragma unroll
  for (int r = 0; r < 16; ++r) {
    int row = m0 + 32*ti + (r & 3) + 8*(r >> 2) + 4*u2;
    int col = n0 + brl;
    float c = acc[r] + bias[col];
    c = 0.5f*c*(1.f + erff(c*0.70710678118654752f));
    C[(size_t)row*N + col] = c;
  }
}

// ---- K4: logits = hh @ w2^T + b2 ; one wave per batch row ----
__global__ __launch_bounds__(256) void k_logits(
    const float* __restrict__ hh, const float* __restrict__ w2,
    const float* __restrict__ b2, float* __restrict__ out)
{
  const int w = threadIdx.x >> 6, lane = threadIdx.x & 63;
  const int r = blockIdx.x*4 + w;
  const float* hr = hh + (size_t)r*HIDDIM + lane*16;
  float hv[16];
  #pragma unroll
  for (int i4 = 0; i4 < 4; ++i4) {
    float4 v = *(const float4*)(hr + i4*4);
    hv[i4*4+0] = v.x; hv[i4*4+1] = v.y; hv[i4*4+2] = v.z; hv[i4*4+3] = v.w;
  }
  float acc[NCLS];
  #pragma unroll
  for (int c = 0; c < NCLS; ++c) {
    const float* wr = w2 + (size_t)c*HIDDIM + lane*16;
    float a = 0.f;
    #pragma unroll
    for (int i4 = 0; i4 < 4; ++i4) {
      float4 wv = *(const float4*)(wr + i4*4);
      a += hv[i4*4]*wv.x + hv[i4*4+1]*wv.y + hv[i4*4+2]*wv.z + hv[i4*4+3]*wv.w;
    }
    acc[c] = a;
  }
  #pragma unroll
  for (int c = 0; c < NCLS; ++c)
    #pragma unroll
    for (int m = 1; m < 64; m <<= 1) acc[c] += __shfl_xor(acc[c], m, 64);
  if (lane == 0) {
    #pragma unroll
    for (int c = 0; c < NCLS; ++c) out[(size_t)r*NCLS + c] = acc[c] + b2[c];
  }
}

extern "C" void kernel_launch(void* const* d_in, const int* in_sizes, int n_in,
                              void* d_out, int out_size, void* d_ws, size_t ws_size,
                              hipStream_t stream)
{
  const float* x      = (const float*)d_in[0];
  const float* proj_w = (const float*)d_in[1];
  const float* proj_b = (const float*)d_in[2];
  const float* cls    = (const float*)d_in[3];
  const float* pos    = (const float*)d_in[4];
  const float* wq     = (const float*)d_in[5];
  const float* bq     = (const float*)d_in[6];
  const float* wo     = (const float*)d_in[7];
  const float* bo     = (const float*)d_in[8];
  const float* w1     = (const float*)d_in[9];
  const float* b1     = (const float*)d_in[10];
  const float* w2     = (const float*)d_in[11];
  const float* b2     = (const float*)d_in[12];
  float* out = (float*)d_out;

  // ws layout (bytes), total ~14.9 MB (prev rounds used 20.15 MB OK).
  // wqT overlays hh: written by k_prep, read by k_qbias, overwritten by k_gemm2.
  unsigned short* WcH  = (unsigned short*)d_ws;                        // 49152
  unsigned short* WcL  = (unsigned short*)((char*)d_ws + 49152);       // 49152
  float* qbias         = (float*)((char*)d_ws + 98304);                // 133120
  unsigned short* W1cH = (unsigned short*)((char*)d_ws + 231424);      // 1 MB
  unsigned short* W1cL = (unsigned short*)((char*)d_ws + 1280000);     // 1 MB
  float* b1c           = (float*)((char*)d_ws + 2328576);              // 4 KB
  unsigned short* mh0H = (unsigned short*)((char*)d_ws + 2332672);     // 2 MB
  unsigned short* mh0L = (unsigned short*)((char*)d_ws + 4429824);     // 2 MB
  float* hh            = (float*)((char*)d_ws + 6526976);              // 8 MB
  float* wqT           = hh;                                           // 1 MB overlay

  hipLaunchKernelGGL(k_prep, dim3(768), dim3(256), 0, stream,
                     wq, proj_w, WcH, WcL, wqT);
  hipLaunchKernelGGL(k_qbias, dim3(NHEADS*SEQL), dim3(256), 0, stream,
                     wqT, bq, cls, pos, proj_b, qbias);
  hipLaunchKernelGGL(k_fuse, dim3(HIDDIM/64, EMB/64), dim3(256), 0, stream,
                     w1, wo, W1cH, W1cL);
  hipLaunchKernelGGL(k_b1c, dim3(HIDDIM/256), dim3(256), 0, stream,
                     w1, bo, b1, b1c);
  hipLaunchKernelGGL(k_attn, dim3(BATCH*NHEADS), dim3(256), 0, stream,
                     x, WcH, WcL, qbias, mh0H, mh0L);
  hipLaunchKernelGGL(k_gemm2, dim3(BATCH/64, HIDDIM/64), dim3(256), 0, stream,
                     mh0H, mh0L, W1cH, W1cL, b1c, hh, HIDDIM, EMB);
  hipLaunchKernelGGL(k_logits, dim3(BATCH/4), dim3(256), 0, stream,
                     hh, w2, b2, out);
}